// Round 2
// baseline (188.627 us; speedup 1.0000x reference)
//
#include <hip/hip_runtime.h>

// DequantSiluAndMulQuant: x int32 [8192, 22016], scale f32 scalar.
// d = 11008. tmp = silu(x[:, :d]*s) * (x[:, d:]*s)
// row_scale = max|tmp| / 127 ; q = clip(rint(tmp/row_scale), -128, 127)
// d_out (float32): q flat [8192*11008] followed by row_scale [8192].

constexpr int NUM_TOKENS = 8192;
constexpr int TWO_D      = 22016;
constexpr int D          = TWO_D / 2;        // 11008
constexpr int VEC        = D / 4;            // 2752 int4 per half-row
constexpr int THREADS    = 256;
constexpr int FULL_ITERS = VEC / THREADS;    // 10
constexpr int REM        = VEC % THREADS;    // 192

typedef int   i32x4 __attribute__((ext_vector_type(4)));
typedef float f32x4 __attribute__((ext_vector_type(4)));

__device__ __forceinline__ float silu_mul(float g, float u) {
    // silu(g) * u = g / (1 + exp(-g)) * u
    return g / (1.0f + __expf(-g)) * u;
}

__global__ __launch_bounds__(THREADS)
void dsmq_kernel(const i32x4* __restrict__ x,
                 const float* __restrict__ dsp,
                 f32x4* __restrict__ qout,
                 float* __restrict__ sout)
{
    const int row = blockIdx.x;
    const int t   = threadIdx.x;
    const float ds = *dsp;

    const i32x4* gp = x + (size_t)row * (TWO_D / 4);
    const i32x4* up = gp + VEC;

    f32x4 tmp[FULL_ITERS + 1];
    float m = 0.0f;

#pragma unroll
    for (int k = 0; k <= FULL_ITERS; ++k) {
        const int idx = k * THREADS + t;
        if (k < FULL_ITERS || t < REM) {
            const i32x4 gv = __builtin_nontemporal_load(&gp[idx]);
            const i32x4 uv = __builtin_nontemporal_load(&up[idx]);
            f32x4 r;
            r.x = silu_mul((float)gv.x * ds, (float)uv.x * ds);
            r.y = silu_mul((float)gv.y * ds, (float)uv.y * ds);
            r.z = silu_mul((float)gv.z * ds, (float)uv.z * ds);
            r.w = silu_mul((float)gv.w * ds, (float)uv.w * ds);
            tmp[k] = r;
            m = fmaxf(m, fmaxf(fmaxf(fabsf(r.x), fabsf(r.y)),
                               fmaxf(fabsf(r.z), fabsf(r.w))));
        }
    }

    // wave-level max reduce across 64 lanes
#pragma unroll
    for (int off = 32; off >= 1; off >>= 1)
        m = fmaxf(m, __shfl_xor(m, off, 64));

    __shared__ float smax[THREADS / 64];
    const int wave = t >> 6;
    if ((t & 63) == 0) smax[wave] = m;
    __syncthreads();
    m = fmaxf(fmaxf(smax[0], smax[1]), fmaxf(smax[2], smax[3]));

    const float scale = m / 127.0f;
    const float inv   = (m > 0.0f) ? 127.0f / m : 0.0f;

    if (t == 0) sout[row] = scale;

    f32x4* qp = qout + (size_t)row * VEC;
#pragma unroll
    for (int k = 0; k <= FULL_ITERS; ++k) {
        const int idx = k * THREADS + t;
        if (k < FULL_ITERS || t < REM) {
            const f32x4 r = tmp[k];
            f32x4 q;
            q.x = fminf(fmaxf(rintf(r.x * inv), -128.0f), 127.0f);
            q.y = fminf(fmaxf(rintf(r.y * inv), -128.0f), 127.0f);
            q.z = fminf(fmaxf(rintf(r.z * inv), -128.0f), 127.0f);
            q.w = fminf(fmaxf(rintf(r.w * inv), -128.0f), 127.0f);
            __builtin_nontemporal_store(q, &qp[idx]);
        }
    }
}

extern "C" void kernel_launch(void* const* d_in, const int* in_sizes, int n_in,
                              void* d_out, int out_size, void* d_ws, size_t ws_size,
                              hipStream_t stream)
{
    const i32x4* x  = (const i32x4*)d_in[0];
    const float* ds = (const float*)d_in[1];
    f32x4* qout = (f32x4*)d_out;
    float* sout = (float*)d_out + (size_t)NUM_TOKENS * D;
    dsmq_kernel<<<NUM_TOKENS, THREADS, 0, stream>>>(x, ds, qout, sout);
}

// Round 3
// 181.044 us; speedup vs baseline: 1.0419x; 1.0419x over previous
//
#include <hip/hip_runtime.h>

// DequantSiluAndMulQuant: x int32 [8192, 22016], scale f32 scalar.
// d = 11008. tmp = silu(x[:, :d]*s) * (x[:, d:]*s)
// row_scale = max|tmp| / 127 ; q = clip(rint(tmp/row_scale), -128, 127)
// d_out (float32): q flat [8192*11008] followed by row_scale [8192].

constexpr int NUM_TOKENS = 8192;
constexpr int TWO_D      = 22016;
constexpr int D          = TWO_D / 2;        // 11008
constexpr int VEC        = D / 4;            // 2752 float4 per half-row
constexpr int THREADS    = 512;
constexpr int NWAVES     = THREADS / 64;     // 8
constexpr int FULL_ITERS = VEC / THREADS;    // 5
constexpr int REM        = VEC % THREADS;    // 192

typedef int   i32x4 __attribute__((ext_vector_type(4)));
typedef float f32x4 __attribute__((ext_vector_type(4)));

__device__ __forceinline__ float silu_mul(float g, float u) {
    // silu(g)*u = g * rcp(1 + exp(-g)) * u   (v_rcp_f32: 1 ulp, plenty for int8 quant)
    return g * __builtin_amdgcn_rcpf(1.0f + __expf(-g)) * u;
}

__global__ __launch_bounds__(THREADS)
void dsmq_kernel(const i32x4* __restrict__ x,
                 const float* __restrict__ dsp,
                 f32x4* __restrict__ qout,
                 float* __restrict__ sout)
{
    const int row = blockIdx.x;
    const int t   = threadIdx.x;
    const float ds = *dsp;

    const i32x4* gp = x + (size_t)row * (TWO_D / 4);
    const i32x4* up = gp + VEC;

    f32x4 tmp[FULL_ITERS + 1];
    float m = 0.0f;

#pragma unroll
    for (int k = 0; k <= FULL_ITERS; ++k) {
        const int idx = k * THREADS + t;
        if (k < FULL_ITERS || t < REM) {
            const i32x4 gv = __builtin_nontemporal_load(&gp[idx]);
            const i32x4 uv = __builtin_nontemporal_load(&up[idx]);
            f32x4 r;
            r.x = silu_mul((float)gv.x * ds, (float)uv.x * ds);
            r.y = silu_mul((float)gv.y * ds, (float)uv.y * ds);
            r.z = silu_mul((float)gv.z * ds, (float)uv.z * ds);
            r.w = silu_mul((float)gv.w * ds, (float)uv.w * ds);
            tmp[k] = r;
            m = fmaxf(m, fmaxf(fmaxf(fabsf(r.x), fabsf(r.y)),
                               fmaxf(fabsf(r.z), fabsf(r.w))));
        }
    }

    // wave-level max reduce across 64 lanes
#pragma unroll
    for (int off = 32; off >= 1; off >>= 1)
        m = fmaxf(m, __shfl_xor(m, off, 64));

    __shared__ float smax[NWAVES];
    const int wave = t >> 6;
    if ((t & 63) == 0) smax[wave] = m;
    __syncthreads();
    m = smax[0];
#pragma unroll
    for (int w = 1; w < NWAVES; ++w) m = fmaxf(m, smax[w]);

    const float scale = m / 127.0f;
    const float inv   = (m > 0.0f) ? 127.0f / m : 0.0f;

    if (t == 0) sout[row] = scale;

    f32x4* qp = qout + (size_t)row * VEC;
#pragma unroll
    for (int k = 0; k <= FULL_ITERS; ++k) {
        const int idx = k * THREADS + t;
        if (k < FULL_ITERS || t < REM) {
            const f32x4 r = tmp[k];
            f32x4 q;
            q.x = fminf(fmaxf(rintf(r.x * inv), -128.0f), 127.0f);
            q.y = fminf(fmaxf(rintf(r.y * inv), -128.0f), 127.0f);
            q.z = fminf(fmaxf(rintf(r.z * inv), -128.0f), 127.0f);
            q.w = fminf(fmaxf(rintf(r.w * inv), -128.0f), 127.0f);
            __builtin_nontemporal_store(q, &qp[idx]);
        }
    }
}

extern "C" void kernel_launch(void* const* d_in, const int* in_sizes, int n_in,
                              void* d_out, int out_size, void* d_ws, size_t ws_size,
                              hipStream_t stream)
{
    const i32x4* x  = (const i32x4*)d_in[0];
    const float* ds = (const float*)d_in[1];
    f32x4* qout = (f32x4*)d_out;
    float* sout = (float*)d_out + (size_t)NUM_TOKENS * D;
    dsmq_kernel<<<NUM_TOKENS, THREADS, 0, stream>>>(x, ds, qout, sout);
}